// Round 3
// baseline (25566.631 us; speedup 1.0000x reference)
//
#include <hip/hip_runtime.h>
#include <math.h>

#define HDIM  1024
#define VDIM  50257
#define NBLK  256
#define NTHR  1024
#define NWAVE 16
#define DELTA 1e-3f

typedef unsigned int uint;

// ---------------- ws layout ----------------
#define WS_GATES   0         // 2*4096 f32 = 32 KiB (double-buffered gates)
#define WS_PSOFT   32768     // 256 f32  block softmax-max
#define WS_PARGV   33792     // 256 f32  block argmax value (fp32-exact)
#define WS_PARGI   34816     // 256 i32  block argmax index
#define WS_PSUM    35840     // 256 f32  block exp-sum
#define WS_ARRIVE  36864     // 256 slots * 128 B
#define WS_DONE    69632     // 128 B
#define WS_ZOFF    32768
#define WS_ZLEN    36992     // zero 32768..69760 each launch
#define WS_WBF     131072    // bf16 W_out (optional)
#define WBF_BYTES  ((size_t)VDIM * HDIM * 2)

__device__ __forceinline__ float dot4(float4 a, float4 b) {
  return a.x * b.x + a.y * b.y + a.z * b.z + a.w * b.w;
}

__device__ __forceinline__ float wred64(float v) {
  v += __shfl_xor(v, 32); v += __shfl_xor(v, 16); v += __shfl_xor(v, 8);
  v += __shfl_xor(v, 4);  v += __shfl_xor(v, 2);  v += __shfl_xor(v, 1);
  return v;
}

__device__ __forceinline__ void wmax64(float& v, int& i) {
#pragma unroll
  for (int off = 32; off > 0; off >>= 1) {
    float v2 = __shfl_xor(v, off);
    int   i2 = __shfl_xor(i, off);
    if (v2 > v || (v2 == v && i2 < i)) { v = v2; i = i2; }
  }
}

__device__ __forceinline__ float wvmax64(float v) {
#pragma unroll
  for (int off = 32; off > 0; off >>= 1) v = fmaxf(v, __shfl_xor(v, off));
  return v;
}

// bf16 chunk (8 values packed in uint4) dot 8 consecutive f32
__device__ __forceinline__ float dot8(uint4 u, const float* hp) {
  float s;
  s  = __uint_as_float(u.x << 16)         * hp[0];
  s += __uint_as_float(u.x & 0xffff0000u) * hp[1];
  s += __uint_as_float(u.y << 16)         * hp[2];
  s += __uint_as_float(u.y & 0xffff0000u) * hp[3];
  s += __uint_as_float(u.z << 16)         * hp[4];
  s += __uint_as_float(u.z & 0xffff0000u) * hp[5];
  s += __uint_as_float(u.w << 16)         * hp[6];
  s += __uint_as_float(u.w & 0xffff0000u) * hp[7];
  return s;
}

// Slot-based grid barrier: per-block 128B arrival slots (plain release
// stores, no RMW contention); block 0 spin-reads all slots then
// release-stores `done`; others acquire-spin on `done` (loads don't
// serialize). Monotonic round counter, zeroed on-stream each launch.
__device__ __forceinline__ void gbar(uint* arrive, uint* done, int r) {
  __syncthreads();
  if (blockIdx.x == 0) {
    if (threadIdx.x < NBLK - 1) {
      uint* slot = arrive + (threadIdx.x + 1) * 32;
      while (__hip_atomic_load(slot, __ATOMIC_ACQUIRE,
                               __HIP_MEMORY_SCOPE_AGENT) < (uint)r)
        __builtin_amdgcn_s_sleep(1);
    }
    __syncthreads();
    if (threadIdx.x == 0)
      __hip_atomic_store(done, (uint)r, __ATOMIC_RELEASE,
                         __HIP_MEMORY_SCOPE_AGENT);
  } else {
    if (threadIdx.x == 0) {
      __hip_atomic_store(arrive + blockIdx.x * 32, (uint)r, __ATOMIC_RELEASE,
                         __HIP_MEMORY_SCOPE_AGENT);
      while (__hip_atomic_load(done, __ATOMIC_ACQUIRE,
                               __HIP_MEMORY_SCOPE_AGENT) < (uint)r)
        __builtin_amdgcn_s_sleep(1);
    }
    __syncthreads();
  }
}

// fp32 -> bf16 (RNE) converter, run each launch into d_ws
__global__ void conv_kernel(const float* __restrict__ W,
                            ushort* __restrict__ o, int n4) {
  int i = blockIdx.x * blockDim.x + threadIdx.x;
  int stride = gridDim.x * blockDim.x;
  for (; i < n4; i += stride) {
    float4 f = ((const float4*)W)[i];
    ushort4 u;
    uint b;
    b = __float_as_uint(f.x); u.x = (ushort)((b + 0x7fffu + ((b >> 16) & 1u)) >> 16);
    b = __float_as_uint(f.y); u.y = (ushort)((b + 0x7fffu + ((b >> 16) & 1u)) >> 16);
    b = __float_as_uint(f.z); u.z = (ushort)((b + 0x7fffu + ((b >> 16) & 1u)) >> 16);
    b = __float_as_uint(f.w); u.w = (ushort)((b + 0x7fffu + ((b >> 16) & 1u)) >> 16);
    ((ushort4*)o)[i] = u;
  }
}

#define LOADB(JB, P)                                                          \
  {                                                                           \
    int n_ = count - (JB);                                                    \
    const ushort* b_ = Wbf + (size_t)(start + (JB)) * HDIM;                   \
    const uint4* r0_ = (const uint4*)b_;                                      \
    const uint4* r1_ = (const uint4*)(b_ + (n_ > 1 ? 1 : 0) * HDIM);          \
    const uint4* r2_ = (const uint4*)(b_ + (n_ > 2 ? 2 : 0) * HDIM);          \
    const uint4* r3_ = (const uint4*)(b_ + (n_ > 3 ? 3 : 0) * HDIM);          \
    P##0 = r0_[lane]; P##1 = r0_[lane + 64];                                  \
    P##2 = r1_[lane]; P##3 = r1_[lane + 64];                                  \
    P##4 = r2_[lane]; P##5 = r2_[lane + 64];                                  \
    P##6 = r3_[lane]; P##7 = r3_[lane + 64];                                  \
  }

template <int BF>
__global__ void __launch_bounds__(NTHR, 4)
seq2seq_kernel(const int* __restrict__ source, int S,
               const int* __restrict__ n_steps_p, const int* __restrict__ start_tok_p,
               const float* __restrict__ Wemb_enc,
               const float* __restrict__ W_ih_e, const float* __restrict__ W_hh_e,
               const float* __restrict__ b_ih_e, const float* __restrict__ b_hh_e,
               const float* __restrict__ Wemb_dec,
               const float* __restrict__ W_ih_d, const float* __restrict__ W_hh_d,
               const float* __restrict__ b_ih_d, const float* __restrict__ b_hh_d,
               const float* __restrict__ W_out, const float* __restrict__ b_out,
               const ushort* __restrict__ Wbf,
               float* __restrict__ out,
               float* gates, float* psoft, float* pargv, int* pargi, float* psum,
               uint* arrive, uint* done)
{
  const int tid  = threadIdx.x;
  const int blk  = blockIdx.x;
  const int wave = tid >> 6;
  const int lane = tid & 63;

  __shared__ float4 x4[2][HDIM / 4];
  __shared__ float4 h4[HDIM / 4];
  __shared__ float  c_lds[HDIM];
  __shared__ float  e_lds[200];
  __shared__ float  red_v[NWAVE];
  __shared__ int    red_i[NWAVE];
  __shared__ float  red_s[NWAVE];
  __shared__ float  red_m[NWAVE];

  float* h_s = (float*)h4;

  h_s[tid] = 0.f;
  c_lds[tid] = 0.f;

  // ---- pin encoder LSTM weight slice in VGPRs (1 row/wave, 8 f4/thread) ----
  const int r_e = blk * NWAVE + wave;
  float4 wie[4], whe[4];
  {
    const float4* pie = (const float4*)(W_ih_e + (size_t)r_e * HDIM);
    const float4* phe = (const float4*)(W_hh_e + (size_t)r_e * HDIM);
#pragma unroll
    for (int c = 0; c < 4; ++c) {
      wie[c] = pie[lane + 64 * c];
      whe[c] = phe[lane + 64 * c];
    }
  }
  const float bse = b_ih_e[r_e] + b_hh_e[r_e];

  if (tid < 256)
    x4[0][tid] = ((const float4*)(Wemb_enc + (size_t)source[0] * HDIM))[tid];
  __syncthreads();

  int rnd = 0, gstep = 0, xb = 0;

  // ================= encoder =================
  for (int t = 0; t < S; ++t) {
    float4 pf;
    const bool havepf = (t + 1 < S) && (tid < 256);
    if (havepf)
      pf = ((const float4*)(Wemb_enc + (size_t)source[t + 1] * HDIM))[tid];

    float g = bse;
    const float4* xf = (const float4*)&x4[xb][0];
#pragma unroll
    for (int c = 0; c < 4; ++c) {
      g += dot4(wie[c], xf[lane + 64 * c]);
      g += dot4(whe[c], h4[lane + 64 * c]);
    }
    g = wred64(g);
    float* gcur = gates + (gstep & 1) * 4096;
    if (lane == 0) gcur[r_e] = g;

    gbar(arrive, done, ++rnd);

    {
      float ig = gcur[tid], fg = gcur[tid + 1024];
      float gv = gcur[tid + 2048], og = gcur[tid + 3072];
      float ii = 1.f / (1.f + expf(-ig));
      float ff = 1.f / (1.f + expf(-fg));
      float gt = tanhf(gv);
      float oo = 1.f / (1.f + expf(-og));
      float cc = ff * c_lds[tid] + ii * gt;
      c_lds[tid] = cc;
      h_s[tid]   = oo * tanhf(cc);
    }
    if (havepf) x4[xb ^ 1][tid] = pf;
    __syncthreads();
    xb ^= 1;
    ++gstep;
  }

  // ================= decoder =================
  const int nsteps = n_steps_p[0];
  const int r_d = blk * NWAVE + wave;
  const float bsd = b_ih_d[r_d] + b_hh_d[r_d];
  const float4* pid = (const float4*)(W_ih_d + (size_t)r_d * HDIM);
  const float4* phd = (const float4*)(W_hh_d + (size_t)r_d * HDIM);

  const int start = blk * 196 + (blk < 81 ? blk : 81);
  const int count = 196 + (blk < 81 ? 1 : 0);

  float4 pfx;
  if (tid < 256)
    pfx = ((const float4*)(Wemb_dec + (size_t)start_tok_p[0] * HDIM))[tid];

  for (int t = 0; t < nsteps; ++t) {
    if (tid < 256) x4[0][tid] = pfx;
    __syncthreads();

    // ---- LSTM gates (streamed, 8 f4 loads issued together) ----
    {
      const float4* xf = (const float4*)&x4[0][0];
      float4 a0 = pid[lane], a1 = pid[lane + 64], a2 = pid[lane + 128], a3 = pid[lane + 192];
      float4 b0 = phd[lane], b1 = phd[lane + 64], b2 = phd[lane + 128], b3 = phd[lane + 192];
      float g = bsd;
      g += dot4(a0, xf[lane])       + dot4(b0, h4[lane]);
      g += dot4(a1, xf[lane + 64])  + dot4(b1, h4[lane + 64]);
      g += dot4(a2, xf[lane + 128]) + dot4(b2, h4[lane + 128]);
      g += dot4(a3, xf[lane + 192]) + dot4(b3, h4[lane + 192]);
      g = wred64(g);
      float* gcur = gates + (gstep & 1) * 4096;
      if (lane == 0) gcur[r_d] = g;
    }
    gbar(arrive, done, ++rnd);  // (A)
    {
      const float* gcur = gates + (gstep & 1) * 4096;
      float ig = gcur[tid], fg = gcur[tid + 1024];
      float gv = gcur[tid + 2048], og = gcur[tid + 3072];
      float ii = 1.f / (1.f + expf(-ig));
      float ff = 1.f / (1.f + expf(-fg));
      float gt = tanhf(gv);
      float oo = 1.f / (1.f + expf(-og));
      float cc = ff * c_lds[tid] + ii * gt;
      c_lds[tid] = cc;
      h_s[tid]   = oo * tanhf(cc);
    }
    ++gstep;
    __syncthreads();

    // ---- logit scan ----
    if (BF) {
      int jb = wave * 4;
      if (jb < count) {
        uint4 cu0, cu1, cu2, cu3, cu4, cu5, cu6, cu7;
        LOADB(jb, cu);
        for (; jb < count; jb += NWAVE * 4) {
          int nj = jb + NWAVE * 4;
          bool hn = nj < count;
          uint4 nu0, nu1, nu2, nu3, nu4, nu5, nu6, nu7;
          if (hn) LOADB(nj, nu);
          const float* hp0 = h_s + lane * 8;
          const float* hp1 = h_s + lane * 8 + 512;
          float a0 = dot8(cu0, hp0) + dot8(cu1, hp1);
          float a1 = dot8(cu2, hp0) + dot8(cu3, hp1);
          float a2 = dot8(cu4, hp0) + dot8(cu5, hp1);
          float a3 = dot8(cu6, hp0) + dot8(cu7, hp1);
          a0 = wred64(a0); a1 = wred64(a1); a2 = wred64(a2); a3 = wred64(a3);
          if (lane == 0) {
            int n_ = count - jb;
            e_lds[jb] = a0 + b_out[start + jb];
            if (n_ > 1) e_lds[jb + 1] = a1 + b_out[start + jb + 1];
            if (n_ > 2) e_lds[jb + 2] = a2 + b_out[start + jb + 2];
            if (n_ > 3) e_lds[jb + 3] = a3 + b_out[start + jb + 3];
          }
          if (hn) {
            cu0 = nu0; cu1 = nu1; cu2 = nu2; cu3 = nu3;
            cu4 = nu4; cu5 = nu5; cu6 = nu6; cu7 = nu7;
          }
        }
      }
    } else {
      for (int jb = wave * 4; jb < count; jb += NWAVE * 4) {
        int n_ = count - jb;
        const float4* r0 = (const float4*)(W_out + (size_t)(start + jb) * HDIM);
        const float4* r1 = (const float4*)(W_out + (size_t)(start + jb + (n_ > 1 ? 1 : 0)) * HDIM);
        const float4* r2 = (const float4*)(W_out + (size_t)(start + jb + (n_ > 2 ? 2 : 0)) * HDIM);
        const float4* r3 = (const float4*)(W_out + (size_t)(start + jb + (n_ > 3 ? 3 : 0)) * HDIM);
        float a0 = 0.f, a1 = 0.f, a2 = 0.f, a3 = 0.f;
#pragma unroll
        for (int c = 0; c < 4; ++c) {
          float4 hh = h4[lane + 64 * c];
          a0 += dot4(r0[lane + 64 * c], hh);
          a1 += dot4(r1[lane + 64 * c], hh);
          a2 += dot4(r2[lane + 64 * c], hh);
          a3 += dot4(r3[lane + 64 * c], hh);
        }
        a0 = wred64(a0); a1 = wred64(a1); a2 = wred64(a2); a3 = wred64(a3);
        if (lane == 0) {
          e_lds[jb] = a0 + b_out[start + jb];
          if (n_ > 1) e_lds[jb + 1] = a1 + b_out[start + jb + 1];
          if (n_ > 2) e_lds[jb + 2] = a2 + b_out[start + jb + 2];
          if (n_ > 3) e_lds[jb + 3] = a3 + b_out[start + jb + 3];
        }
      }
    }
    __syncthreads();

    // ---- block-local max (and, for fp32 path, exact argmax) ----
    float m_soft; float m_arg; int i_arg;
    {
      float v = -INFINITY; int idx = 0x7fffffff;
      if (tid < count) { v = e_lds[tid]; idx = start + tid; }
      wmax64(v, idx);
      if (lane == 0) { red_v[wave] = v; red_i[wave] = idx; }
    }
    __syncthreads();
    {
      float v = red_v[0]; int idx = red_i[0];
#pragma unroll
      for (int w = 1; w < NWAVE; ++w) {
        float v2 = red_v[w]; int i2 = red_i[w];
        if (v2 > v || (v2 == v && i2 < idx)) { v = v2; idx = i2; }
      }
      m_soft = v; m_arg = v; i_arg = idx;
    }
    __syncthreads();

    // ---- exp-sum partial (bf16-based logits) ----
    float pe = 0.f;
    if (tid < count) pe = expf(e_lds[tid] - m_soft);
    {
      float ls = wred64(pe);
      if (lane == 0) red_s[wave] = ls;
    }

    // ---- fp32 rescore of near-max candidates (BF path; argmax-exact) ----
    if (BF) {
      float bv = -INFINITY; int bi = 0x7fffffff;
      for (int j = wave; j < count; j += NWAVE) {
        if (e_lds[j] >= m_soft - DELTA) {
          const float4* w = (const float4*)(W_out + (size_t)(start + j) * HDIM);
          float a = dot4(w[lane], h4[lane]) + dot4(w[lane + 64], h4[lane + 64]) +
                    dot4(w[lane + 128], h4[lane + 128]) + dot4(w[lane + 192], h4[lane + 192]);
          a = wred64(a) + b_out[start + j];
          if (a > bv) { bv = a; bi = start + j; }  // j ascending => min idx on ties
        }
      }
      if (lane == 0) { red_v[wave] = bv; red_i[wave] = bi; }
    }
    __syncthreads();
    if (BF) {
      float v = red_v[0]; int idx = red_i[0];
#pragma unroll
      for (int w = 1; w < NWAVE; ++w) {
        float v2 = red_v[w]; int i2 = red_i[w];
        if (v2 > v || (v2 == v && i2 < idx)) { v = v2; idx = i2; }
      }
      m_arg = v; i_arg = idx;
    }
    float lsum = 0.f;
#pragma unroll
    for (int w = 0; w < NWAVE; ++w) lsum += red_s[w];

    if (tid == 0) {
      psoft[blk] = m_soft; pargv[blk] = m_arg; pargi[blk] = i_arg; psum[blk] = lsum;
    }
    gbar(arrive, done, ++rnd);  // (B)

    // ---- global reductions (redundant per block, deterministic) ----
    int tokn; float lmax;
    {
      float gv = -INFINITY; int gi = 0x7fffffff; float msv = -INFINITY;
      if (tid < NBLK) { gv = pargv[tid]; gi = pargi[tid]; msv = psoft[tid]; }
      wmax64(gv, gi);
      msv = wvmax64(msv);
      if (lane == 0) { red_v[wave] = gv; red_i[wave] = gi; red_m[wave] = msv; }
    }
    __syncthreads();
    {
      float v = red_v[0]; int idx = red_i[0]; float m = red_m[0];
#pragma unroll
      for (int w = 1; w < NWAVE; ++w) {
        float v2 = red_v[w]; int i2 = red_i[w];
        if (v2 > v || (v2 == v && i2 < idx)) { v = v2; idx = i2; }
        m = fmaxf(m, red_m[w]);
      }
      tokn = idx; lmax = m;
    }
    __syncthreads();
    {
      float ss = (tid < NBLK) ? psum[tid] * expf(psoft[tid] - lmax) : 0.f;
      ss = wred64(ss);
      if (lane == 0) red_s[wave] = ss;
    }
    __syncthreads();
    float Ssum = 0.f;
#pragma unroll
    for (int w = 0; w < NWAVE; ++w) Ssum += red_s[w];

    // prefetch next token embedding (in flight across the stores)
    if (tid < 256)
      pfx = ((const float4*)(Wemb_dec + (size_t)tokn * HDIM))[tid];

    float scale = expf(m_soft - lmax) / Ssum;
    if (tid < count)
      out[(size_t)nsteps + (size_t)t * VDIM + start + tid] = pe * scale;
    if (blk == 0 && tid == 0) out[t] = (float)tokn;
  }
}

extern "C" void kernel_launch(void* const* d_in, const int* in_sizes, int n_in,
                              void* d_out, int out_size, void* d_ws, size_t ws_size,
                              hipStream_t stream) {
  const int*   source      = (const int*)d_in[0];
  const int*   n_steps_p   = (const int*)d_in[1];
  const int*   start_tok_p = (const int*)d_in[2];
  const float* Wemb_enc    = (const float*)d_in[3];
  const float* W_ih_e      = (const float*)d_in[4];
  const float* W_hh_e      = (const float*)d_in[5];
  const float* b_ih_e      = (const float*)d_in[6];
  const float* b_hh_e      = (const float*)d_in[7];
  const float* Wemb_dec    = (const float*)d_in[8];
  const float* W_ih_d      = (const float*)d_in[9];
  const float* W_hh_d      = (const float*)d_in[10];
  const float* b_ih_d      = (const float*)d_in[11];
  const float* b_hh_d      = (const float*)d_in[12];
  const float* W_out       = (const float*)d_in[13];
  const float* b_out       = (const float*)d_in[14];
  float*       out         = (float*)d_out;
  int          S           = in_sizes[0];

  char* ws = (char*)d_ws;
  float*  gates  = (float*)(ws + WS_GATES);
  float*  psoft  = (float*)(ws + WS_PSOFT);
  float*  pargv  = (float*)(ws + WS_PARGV);
  int*    pargi  = (int*)  (ws + WS_PARGI);
  float*  psum   = (float*)(ws + WS_PSUM);
  uint*   arrive = (uint*) (ws + WS_ARRIVE);
  uint*   done   = (uint*) (ws + WS_DONE);
  ushort* Wbf    = (ushort*)(ws + WS_WBF);

  bool use_bf = ws_size >= (size_t)WS_WBF + WBF_BYTES;

  // zero barrier slots/done (+partials) every launch -> replay-deterministic
  hipMemsetAsync(ws + WS_ZOFF, 0, WS_ZLEN, stream);

  if (use_bf)
    conv_kernel<<<2048, 256, 0, stream>>>(W_out, Wbf, VDIM * HDIM / 4);

  void* args[] = { &source, &S, &n_steps_p, &start_tok_p, &Wemb_enc,
                   &W_ih_e, &W_hh_e, &b_ih_e, &b_hh_e, &Wemb_dec,
                   &W_ih_d, &W_hh_d, &b_ih_d, &b_hh_d, &W_out, &b_out,
                   &Wbf, &out, &gates, &psoft, &pargv, &pargi, &psum,
                   &arrive, &done };

  void* kfn = use_bf ? (void*)seq2seq_kernel<1> : (void*)seq2seq_kernel<0>;
  hipLaunchCooperativeKernel(kfn, dim3(NBLK), dim3(NTHR), args, 0, stream);
}

// Round 4
// 25206.464 us; speedup vs baseline: 1.0143x; 1.0143x over previous
//
#include <hip/hip_runtime.h>
#include <math.h>

#define HDIM  1024
#define VDIM  50257
#define NBLK  256
#define NTHR  512
#define NWAVE 8
#define DELTA 4e-3f

typedef unsigned int uint;

// ---------------- ws layout (identical footprint to round 3) ----------------
#define WS_GATES   0         // 2*4096 f32 = 32 KiB (double-buffered gates)
#define WS_PSOFT   32768     // 256 f32  block bf16-softmax max
#define WS_PARGV   33792     // 256 f32  block argmax value (fp32-exact)
#define WS_PARGI   34816     // 256 i32  block argmax index
#define WS_PSUM    35840     // 256 f32  block exp-sum
#define WS_ARRIVE  36864     // 256 slots * 128 B (per-block arrival, 1 poller each)
#define WS_DONE    69632     // 32 lines * 128 B: [0]=round [1]=tok [2]=lmax [3]=Ssum
#define WS_ZOFF    32768
#define WS_ZLEN    40960     // zero 32768..73728 each launch
#define WS_WBF     131072    // bf16 W_out (optional)
#define WBF_BYTES  ((size_t)VDIM * HDIM * 2)

__device__ __forceinline__ float dot4(float4 a, float4 b) {
  return a.x * b.x + a.y * b.y + a.z * b.z + a.w * b.w;
}

// 8 packed bf16 (uint4) dot 8 f32 held as two float4
__device__ __forceinline__ float dot8(uint4 u, float4 a, float4 b) {
  float s;
  s  = __uint_as_float(u.x << 16)          * a.x;
  s += __uint_as_float(u.x & 0xffff0000u)  * a.y;
  s += __uint_as_float(u.y << 16)          * a.z;
  s += __uint_as_float(u.y & 0xffff0000u)  * a.w;
  s += __uint_as_float(u.z << 16)          * b.x;
  s += __uint_as_float(u.z & 0xffff0000u)  * b.y;
  s += __uint_as_float(u.w << 16)          * b.z;
  s += __uint_as_float(u.w & 0xffff0000u)  * b.w;
  return s;
}

__device__ __forceinline__ float wred32(float v) {
  v += __shfl_xor(v, 16); v += __shfl_xor(v, 8); v += __shfl_xor(v, 4);
  v += __shfl_xor(v, 2);  v += __shfl_xor(v, 1);
  return v;
}

__device__ __forceinline__ float wred64(float v) {
  v += __shfl_xor(v, 32); v += __shfl_xor(v, 16); v += __shfl_xor(v, 8);
  v += __shfl_xor(v, 4);  v += __shfl_xor(v, 2);  v += __shfl_xor(v, 1);
  return v;
}

__device__ __forceinline__ void wmax64(float& v, int& i) {
#pragma unroll
  for (int off = 32; off > 0; off >>= 1) {
    float v2 = __shfl_xor(v, off);
    int   i2 = __shfl_xor(i, off);
    if (v2 > v || (v2 == v && i2 < i)) { v = v2; i = i2; }
  }
}

__device__ __forceinline__ float wvmax64(float v) {
#pragma unroll
  for (int off = 32; off > 0; off >>= 1) v = fmaxf(v, __shfl_xor(v, off));
  return v;
}

__device__ __forceinline__ uint aload_acq(const uint* p) {
  return __hip_atomic_load(p, __ATOMIC_ACQUIRE, __HIP_MEMORY_SCOPE_AGENT);
}
__device__ __forceinline__ uint aload_rlx(const uint* p) {
  return __hip_atomic_load(p, __ATOMIC_RELAXED, __HIP_MEMORY_SCOPE_AGENT);
}
__device__ __forceinline__ float aloadf_rlx(const float* p) {
  return __hip_atomic_load(p, __ATOMIC_RELAXED, __HIP_MEMORY_SCOPE_AGENT);
}
__device__ __forceinline__ int aloadi_rlx(const int* p) {
  return __hip_atomic_load(p, __ATOMIC_RELAXED, __HIP_MEMORY_SCOPE_AGENT);
}
__device__ __forceinline__ void astore_rel(uint* p, uint v) {
  __hip_atomic_store(p, v, __ATOMIC_RELEASE, __HIP_MEMORY_SCOPE_AGENT);
}
__device__ __forceinline__ void astore_rlx(uint* p, uint v) {
  __hip_atomic_store(p, v, __ATOMIC_RELAXED, __HIP_MEMORY_SCOPE_AGENT);
}

// Plain grid barrier: per-block arrival lines (1 poller each: block0's thread
// blk), 32 fanout done-lines (<=8 pollers each). Monotonic round counter.
__device__ __forceinline__ void gbar_plain(uint* arrive, uint* done, uint r) {
  __syncthreads();
  if (blockIdx.x == 0) {
    const int tid = threadIdx.x;
    if (tid >= 1 && tid < NBLK) {
      const uint* slot = arrive + tid * 32;
      while (aload_acq(slot) < r) __builtin_amdgcn_s_sleep(2);
    }
    __syncthreads();
    if (tid < 32) astore_rel(done + tid * 32, r);
  } else {
    if (threadIdx.x == 0) {
      astore_rel(arrive + blockIdx.x * 32, r);
      const uint* dl = done + (blockIdx.x >> 3) * 32;
      while (aload_acq(dl) < r) __builtin_amdgcn_s_sleep(2);
    }
    __syncthreads();
  }
}

// fp32 -> bf16 (RNE) converter, run each launch into d_ws
__global__ void conv_kernel(const float* __restrict__ W,
                            ushort* __restrict__ o, int n4) {
  int i = blockIdx.x * blockDim.x + threadIdx.x;
  int stride = gridDim.x * blockDim.x;
  for (; i < n4; i += stride) {
    float4 f = ((const float4*)W)[i];
    ushort4 u;
    uint b;
    b = __float_as_uint(f.x); u.x = (ushort)((b + 0x7fffu + ((b >> 16) & 1u)) >> 16);
    b = __float_as_uint(f.y); u.y = (ushort)((b + 0x7fffu + ((b >> 16) & 1u)) >> 16);
    b = __float_as_uint(f.z); u.z = (ushort)((b + 0x7fffu + ((b >> 16) & 1u)) >> 16);
    b = __float_as_uint(f.w); u.w = (ushort)((b + 0x7fffu + ((b >> 16) & 1u)) >> 16);
    ((ushort4*)o)[i] = u;
  }
}

template <int BF>
__global__ void __launch_bounds__(NTHR)
seq2seq_kernel(const int* __restrict__ source, int S,
               const int* __restrict__ n_steps_p, const int* __restrict__ start_tok_p,
               const float* __restrict__ Wemb_enc,
               const float* __restrict__ W_ih_e, const float* __restrict__ W_hh_e,
               const float* __restrict__ b_ih_e, const float* __restrict__ b_hh_e,
               const float* __restrict__ Wemb_dec,
               const float* __restrict__ W_ih_d, const float* __restrict__ W_hh_d,
               const float* __restrict__ b_ih_d, const float* __restrict__ b_hh_d,
               const float* __restrict__ W_out, const float* __restrict__ b_out,
               const ushort* __restrict__ Wbf,
               float* __restrict__ out,
               float* gates, float* psoft, float* pargv, int* pargi, float* psum,
               uint* arrive, uint* done)
{
  const int tid  = threadIdx.x;
  const int blk  = blockIdx.x;
  const int wave = tid >> 6;
  const int lane = tid & 63;
  const int l32  = lane & 31;
  const int rh   = lane >> 5;   // which of the wave's 2 rows

  __shared__ float4 x4[2][HDIM / 4];
  __shared__ float4 h4[HDIM / 4];
  __shared__ float  c_lds[HDIM];
  __shared__ float  e_lds[200];
  __shared__ float  red_v[NWAVE];
  __shared__ int    red_i[NWAVE];
  __shared__ float  red_s[NWAVE];
  __shared__ float  red_m[NWAVE];
  __shared__ float  red_v2[NWAVE];
  __shared__ int    red_i2[NWAVE];
  __shared__ int    sh_tok;
  __shared__ float  sh_lmax, sh_S;

  float* h_s = (float*)h4;

  for (int j = tid; j < HDIM; j += NTHR) { h_s[j] = 0.f; c_lds[j] = 0.f; }

  // ---- pin encoder LSTM weight slice in VGPRs (2 rows/wave, 16 f4/thread) ----
  const int r_e = blk * 16 + wave * 2 + rh;
  float4 wie[8], whe[8];
  {
    const float4* pie = (const float4*)(W_ih_e + (size_t)r_e * HDIM);
    const float4* phe = (const float4*)(W_hh_e + (size_t)r_e * HDIM);
#pragma unroll
    for (int c = 0; c < 8; ++c) { wie[c] = pie[l32 + 32 * c]; whe[c] = phe[l32 + 32 * c]; }
  }
  const float bse = b_ih_e[r_e] + b_hh_e[r_e];

  if (tid < 256)
    x4[0][tid] = ((const float4*)(Wemb_enc + (size_t)source[0] * HDIM))[tid];
  __syncthreads();

  uint rnd = 0;
  int gstep = 0, xb = 0;

  // ================= encoder =================
  for (int t = 0; t < S; ++t) {
    float4 pf;
    const bool havepf = (t + 1 < S) && (tid < 256);
    if (havepf)
      pf = ((const float4*)(Wemb_enc + (size_t)source[t + 1] * HDIM))[tid];

    float g = bse;
    const float4* xf = (const float4*)&x4[xb][0];
#pragma unroll
    for (int c = 0; c < 8; ++c) {
      g += dot4(wie[c], xf[l32 + 32 * c]);
      g += dot4(whe[c], h4[l32 + 32 * c]);
    }
    g = wred32(g);
    float* gcur = gates + (gstep & 1) * 4096;
    if (l32 == 0) gcur[r_e] = g;

    gbar_plain(arrive, done, ++rnd);

#pragma unroll
    for (int q = 0; q < 2; ++q) {
      int j = tid + q * NTHR;
      float ig = gcur[j], fg = gcur[j + 1024], gv = gcur[j + 2048], og = gcur[j + 3072];
      float ii = 1.f / (1.f + expf(-ig));
      float ff = 1.f / (1.f + expf(-fg));
      float gt = tanhf(gv);
      float oo = 1.f / (1.f + expf(-og));
      float cc = ff * c_lds[j] + ii * gt;
      c_lds[j] = cc;
      h_s[j]   = oo * tanhf(cc);
    }
    if (havepf) x4[xb ^ 1][tid] = pf;
    __syncthreads();
    xb ^= 1;
    ++gstep;
  }

  // ================= decoder =================
  const int nsteps = n_steps_p[0];
  const int r_d = blk * 16 + wave * 2 + rh;
  const float bsd = b_ih_d[r_d] + b_hh_d[r_d];
  const float4* pid = (const float4*)(W_ih_d + (size_t)r_d * HDIM);
  const float4* phd = (const float4*)(W_hh_d + (size_t)r_d * HDIM);

  const int start = blk * 196 + (blk < 81 ? blk : 81);
  const int count = 196 + (blk < 81 ? 1 : 0);

  float4 pfx;
  if (tid < 256)
    pfx = ((const float4*)(Wemb_dec + (size_t)start_tok_p[0] * HDIM))[tid];

  for (int t = 0; t < nsteps; ++t) {
    if (tid < 256) x4[0][tid] = pfx;
    __syncthreads();

    // ---- LSTM gates (streamed; 16 f4 loads in flight; 1 row per half-wave) ----
    {
      const float4* xf = (const float4*)&x4[0][0];
      float g = bsd;
#pragma unroll
      for (int c = 0; c < 8; ++c) {
        g += dot4(pid[l32 + 32 * c], xf[l32 + 32 * c]);
        g += dot4(phd[l32 + 32 * c], h4[l32 + 32 * c]);
      }
      g = wred32(g);
      float* gcur = gates + (gstep & 1) * 4096;
      if (l32 == 0) gcur[r_d] = g;
    }
    gbar_plain(arrive, done, ++rnd);  // (A)
    {
      const float* gcur = gates + (gstep & 1) * 4096;
#pragma unroll
      for (int q = 0; q < 2; ++q) {
        int j = tid + q * NTHR;
        float ig = gcur[j], fg = gcur[j + 1024], gv = gcur[j + 2048], og = gcur[j + 3072];
        float ii = 1.f / (1.f + expf(-ig));
        float ff = 1.f / (1.f + expf(-fg));
        float gt = tanhf(gv);
        float oo = 1.f / (1.f + expf(-og));
        float cc = ff * c_lds[j] + ii * gt;
        c_lds[j] = cc;
        h_s[j]   = oo * tanhf(cc);
      }
    }
    ++gstep;
    __syncthreads();

    // ---- logit scan ----
    if (BF) {
      // h slice pinned in registers: lane covers elements [8l,8l+8) and [512+8l,512+8l+8)
      float4 ha0 = h4[2 * lane], ha1 = h4[2 * lane + 1];
      float4 hb0 = h4[128 + 2 * lane], hb1 = h4[128 + 2 * lane + 1];
      for (int jb = wave * 4; jb < count; jb += NWAVE * 4) {
        int n_ = count - jb;
        const ushort* bb = Wbf + (size_t)(start + jb) * HDIM;
        const uint4* r0 = (const uint4*)bb;
        const uint4* r1 = (const uint4*)(bb + (n_ > 1 ? HDIM : 0));
        const uint4* r2 = (const uint4*)(bb + (n_ > 2 ? 2 * HDIM : 0));
        const uint4* r3 = (const uint4*)(bb + (n_ > 3 ? 3 * HDIM : 0));
        uint4 u0 = r0[lane], u1 = r0[lane + 64];
        uint4 u2 = r1[lane], u3 = r1[lane + 64];
        uint4 u4 = r2[lane], u5 = r2[lane + 64];
        uint4 u6 = r3[lane], u7 = r3[lane + 64];
        float a0 = dot8(u0, ha0, ha1) + dot8(u1, hb0, hb1);
        float a1 = dot8(u2, ha0, ha1) + dot8(u3, hb0, hb1);
        float a2 = dot8(u4, ha0, ha1) + dot8(u5, hb0, hb1);
        float a3 = dot8(u6, ha0, ha1) + dot8(u7, hb0, hb1);
        a0 = wred64(a0); a1 = wred64(a1); a2 = wred64(a2); a3 = wred64(a3);
        if (lane == 0) {
          e_lds[jb] = a0 + b_out[start + jb];
          if (n_ > 1) e_lds[jb + 1] = a1 + b_out[start + jb + 1];
          if (n_ > 2) e_lds[jb + 2] = a2 + b_out[start + jb + 2];
          if (n_ > 3) e_lds[jb + 3] = a3 + b_out[start + jb + 3];
        }
      }
    } else {
      for (int jb = wave * 4; jb < count; jb += NWAVE * 4) {
        int n_ = count - jb;
        const float4* r0 = (const float4*)(W_out + (size_t)(start + jb) * HDIM);
        const float4* r1 = (const float4*)(W_out + (size_t)(start + jb + (n_ > 1 ? 1 : 0)) * HDIM);
        const float4* r2 = (const float4*)(W_out + (size_t)(start + jb + (n_ > 2 ? 2 : 0)) * HDIM);
        const float4* r3 = (const float4*)(W_out + (size_t)(start + jb + (n_ > 3 ? 3 : 0)) * HDIM);
        float a0 = 0.f, a1 = 0.f, a2 = 0.f, a3 = 0.f;
#pragma unroll
        for (int c = 0; c < 4; ++c) {
          float4 hh = h4[lane + 64 * c];
          a0 += dot4(r0[lane + 64 * c], hh);
          a1 += dot4(r1[lane + 64 * c], hh);
          a2 += dot4(r2[lane + 64 * c], hh);
          a3 += dot4(r3[lane + 64 * c], hh);
        }
        a0 = wred64(a0); a1 = wred64(a1); a2 = wred64(a2); a3 = wred64(a3);
        if (lane == 0) {
          e_lds[jb] = a0 + b_out[start + jb];
          if (n_ > 1) e_lds[jb + 1] = a1 + b_out[start + jb + 1];
          if (n_ > 2) e_lds[jb + 2] = a2 + b_out[start + jb + 2];
          if (n_ > 3) e_lds[jb + 3] = a3 + b_out[start + jb + 3];
        }
      }
    }
    __syncthreads();

    // ---- block-local bf16 max/argmax (np.argmax tie-break: lowest index) ----
    float m_soft; int i_soft;
    {
      float v = -INFINITY; int idx = 0x7fffffff;
      if (tid < count) { v = e_lds[tid]; idx = start + tid; }
      wmax64(v, idx);
      if (lane == 0) { red_v[wave] = v; red_i[wave] = idx; }
    }
    __syncthreads();
    {
      float v = red_v[0]; int idx = red_i[0];
#pragma unroll
      for (int w = 1; w < NWAVE; ++w) {
        float v2 = red_v[w]; int i2 = red_i[w];
        if (v2 > v || (v2 == v && i2 < idx)) { v = v2; idx = i2; }
      }
      m_soft = v; i_soft = idx;
    }

    // ---- exp partial (own value in register) + sum ----
    float pe = (tid < count) ? expf(e_lds[tid] - m_soft) : 0.f;
    {
      float ls = wred64(pe);
      if (lane == 0) red_s[wave] = ls;
    }

    // ---- fp32 rescore of near-max candidates (BF path; argmax-exact) ----
    float m_arg = m_soft; int i_arg = i_soft;
    if (BF) {
      float bv = -INFINITY; int bi = 0x7fffffff;
      for (int j = wave; j < count; j += NWAVE) {   // j wave-uniform
        if (e_lds[j] >= m_soft - DELTA) {
          const float4* w = (const float4*)(W_out + (size_t)(start + j) * HDIM);
          float a = 0.f;
#pragma unroll
          for (int c = 0; c < 4; ++c) a += dot4(w[lane + 64 * c], h4[lane + 64 * c]);
          a = wred64(a) + b_out[start + j];
          if (a > bv) { bv = a; bi = start + j; }   // ascending j => min idx on ties
        }
      }
      if (lane == 0) { red_v2[wave] = bv; red_i2[wave] = bi; }
    }
    __syncthreads();
    float lsum = 0.f;
#pragma unroll
    for (int w = 0; w < NWAVE; ++w) lsum += red_s[w];
    if (BF) {
      float v = red_v2[0]; int idx = red_i2[0];
#pragma unroll
      for (int w = 1; w < NWAVE; ++w) {
        float v2 = red_v2[w]; int i2 = red_i2[w];
        if (v2 > v || (v2 == v && i2 < idx)) { v = v2; idx = i2; }
      }
      m_arg = v; i_arg = idx;
    }

    if (tid == 0) {
      psoft[blk] = m_soft; pargv[blk] = m_arg; pargi[blk] = i_arg; psum[blk] = lsum;
    }

    // ---- barrier B with payload: block0 reduces once, publishes result ----
    ++rnd;
    __syncthreads();
    int tokn; float lmax, Ssum;
    if (blk == 0) {
      if (tid >= 1 && tid < NBLK) {
        const uint* slot = arrive + tid * 32;
        while (aload_acq(slot) < rnd) __builtin_amdgcn_s_sleep(2);
      }
      __syncthreads();
      float v = -INFINITY, m = -INFINITY, mysum = 0.f, myms = 0.f;
      int idx = 0x7fffffff;
      if (tid < NBLK) {
        v     = aloadf_rlx(&pargv[tid]);
        idx   = aloadi_rlx(&pargi[tid]);
        m     = aloadf_rlx(&psoft[tid]);
        mysum = aloadf_rlx(&psum[tid]);
        myms  = m;
      }
      wmax64(v, idx);
      float mm = wvmax64(m);
      if (lane == 0 && wave < 4) { red_v[wave] = v; red_i[wave] = idx; red_m[wave] = mm; }
      __syncthreads();
      {
        float vv = red_v[0]; int ii2 = red_i[0]; float mmax = red_m[0];
#pragma unroll
        for (int w = 1; w < 4; ++w) {
          float v2 = red_v[w]; int i2 = red_i[w];
          if (v2 > vv || (v2 == vv && i2 < ii2)) { vv = v2; ii2 = i2; }
          mmax = fmaxf(mmax, red_m[w]);
        }
        tokn = ii2; lmax = mmax;
      }
      {
        float s = (tid < NBLK) ? mysum * expf(myms - lmax) : 0.f;
        s = wred64(s);
        if (lane == 0 && wave < 4) red_s[wave] = s;
      }
      __syncthreads();
      Ssum = red_s[0] + red_s[1] + red_s[2] + red_s[3];
      if (tid < 32) {
        uint* dl = done + tid * 32;
        astore_rlx(dl + 1, (uint)tokn);
        astore_rlx(dl + 2, __float_as_uint(lmax));
        astore_rlx(dl + 3, __float_as_uint(Ssum));
        astore_rel(dl, rnd);
      }
    } else {
      if (tid == 0) {
        astore_rel(arrive + blk * 32, rnd);
        const uint* dl = done + (blk >> 3) * 32;
        while (aload_acq(dl) < rnd) __builtin_amdgcn_s_sleep(2);
        sh_tok  = (int)aload_rlx(dl + 1);
        sh_lmax = __uint_as_float(aload_rlx(dl + 2));
        sh_S    = __uint_as_float(aload_rlx(dl + 3));
      }
      __syncthreads();
      tokn = sh_tok; lmax = sh_lmax; Ssum = sh_S;
    }

    // prefetch next token's embedding row (hides under the prob stores)
    if (tid < 256)
      pfx = ((const float4*)(Wemb_dec + (size_t)tokn * HDIM))[tid];

    float scale = expf(m_soft - lmax) / Ssum;
    if (tid < count)
      out[(size_t)nsteps + (size_t)t * VDIM + start + tid] = pe * scale;
    if (blk == 0 && tid == 0) out[t] = (float)tokn;
  }
}

extern "C" void kernel_launch(void* const* d_in, const int* in_sizes, int n_in,
                              void* d_out, int out_size, void* d_ws, size_t ws_size,
                              hipStream_t stream) {
  const int*   source      = (const int*)d_in[0];
  const int*   n_steps_p   = (const int*)d_in[1];
  const int*   start_tok_p = (const int*)d_in[2];
  const float* Wemb_enc    = (const float*)d_in[3];
  const float* W_ih_e      = (const float*)d_in[4];
  const float* W_hh_e      = (const float*)d_in[5];
  const float* b_ih_e      = (const float*)d_in[6];
  const float* b_hh_e      = (const float*)d_in[7];
  const float* Wemb_dec    = (const float*)d_in[8];
  const float* W_ih_d      = (const float*)d_in[9];
  const float* W_hh_d      = (const float*)d_in[10];
  const float* b_ih_d      = (const float*)d_in[11];
  const float* b_hh_d      = (const float*)d_in[12];
  const float* W_out       = (const float*)d_in[13];
  const float* b_out       = (const float*)d_in[14];
  float*       out         = (float*)d_out;
  int          S           = in_sizes[0];

  char* ws = (char*)d_ws;
  float*  gates  = (float*)(ws + WS_GATES);
  float*  psoft  = (float*)(ws + WS_PSOFT);
  float*  pargv  = (float*)(ws + WS_PARGV);
  int*    pargi  = (int*)  (ws + WS_PARGI);
  float*  psum   = (float*)(ws + WS_PSUM);
  uint*   arrive = (uint*) (ws + WS_ARRIVE);
  uint*   done   = (uint*) (ws + WS_DONE);
  ushort* Wbf    = (ushort*)(ws + WS_WBF);

  bool use_bf = ws_size >= (size_t)WS_WBF + WBF_BYTES;

  // zero barrier slots/done (+partials) every launch -> replay-deterministic
  hipMemsetAsync(ws + WS_ZOFF, 0, WS_ZLEN, stream);

  if (use_bf)
    conv_kernel<<<2048, 256, 0, stream>>>(W_out, Wbf, VDIM * HDIM / 4);

  void* args[] = { &source, &S, &n_steps_p, &start_tok_p, &Wemb_enc,
                   &W_ih_e, &W_hh_e, &b_ih_e, &b_hh_e, &Wemb_dec,
                   &W_ih_d, &W_hh_d, &b_ih_d, &b_hh_d, &W_out, &b_out,
                   &Wbf, &out, &gates, &psoft, &pargv, &pargi, &psum,
                   &arrive, &done };

  void* kfn = use_bf ? (void*)seq2seq_kernel<1> : (void*)seq2seq_kernel<0>;
  hipLaunchCooperativeKernel(kfn, dim3(NBLK), dim3(NTHR), args, 0, stream);
}

// Round 5
// 6614.045 us; speedup vs baseline: 3.8655x; 3.8111x over previous
//
#include <hip/hip_runtime.h>
#include <math.h>

#define HDIM  1024
#define VDIM  50257
#define NBLK  256
#define NTHR  512
#define NWAVE 8
#define DELTA 4e-3f

typedef unsigned int uint;

// ---------------- ws layout ----------------
#define WS_GATES   0         // 2*4096 f32 = 32 KiB (double-buffered gates)
#define WS_PSOFT   32768     // 256 f32  block bf16-softmax max
#define WS_PARGV   33792     // 256 f32  block argmax value (fp32-exact)
#define WS_PARGI   34816     // 256 i32  block argmax index
#define WS_PSUM    35840     // 256 f32  block exp-sum
#define WS_ARRIVE  36864     // 256 slots * 128 B (per-block arrival, 1 poller each)
#define WS_DONE    69632     // 32 lines * 128 B: [0]=round [1]=tok [2]=lmax [3]=Ssum
#define WS_ZOFF    32768
#define WS_ZLEN    40960     // zero 32768..73728 each launch
#define WS_WBF     131072    // bf16 W_out (optional)
#define WBF_BYTES  ((size_t)VDIM * HDIM * 2)

__device__ __forceinline__ float dot4(float4 a, float4 b) {
  return a.x * b.x + a.y * b.y + a.z * b.z + a.w * b.w;
}

// 8 packed bf16 (uint4) dot 8 f32 held as two float4
__device__ __forceinline__ float dot8(uint4 u, float4 a, float4 b) {
  float s;
  s  = __uint_as_float(u.x << 16)          * a.x;
  s += __uint_as_float(u.x & 0xffff0000u)  * a.y;
  s += __uint_as_float(u.y << 16)          * a.z;
  s += __uint_as_float(u.y & 0xffff0000u)  * a.w;
  s += __uint_as_float(u.z << 16)          * b.x;
  s += __uint_as_float(u.z & 0xffff0000u)  * b.y;
  s += __uint_as_float(u.w << 16)          * b.z;
  s += __uint_as_float(u.w & 0xffff0000u)  * b.w;
  return s;
}

__device__ __forceinline__ float wred32(float v) {
  v += __shfl_xor(v, 16); v += __shfl_xor(v, 8); v += __shfl_xor(v, 4);
  v += __shfl_xor(v, 2);  v += __shfl_xor(v, 1);
  return v;
}

__device__ __forceinline__ float wred64(float v) {
  v += __shfl_xor(v, 32); v += __shfl_xor(v, 16); v += __shfl_xor(v, 8);
  v += __shfl_xor(v, 4);  v += __shfl_xor(v, 2);  v += __shfl_xor(v, 1);
  return v;
}

__device__ __forceinline__ void wmax64(float& v, int& i) {
#pragma unroll
  for (int off = 32; off > 0; off >>= 1) {
    float v2 = __shfl_xor(v, off);
    int   i2 = __shfl_xor(i, off);
    if (v2 > v || (v2 == v && i2 < i)) { v = v2; i = i2; }
  }
}

__device__ __forceinline__ float wvmax64(float v) {
#pragma unroll
  for (int off = 32; off > 0; off >>= 1) v = fmaxf(v, __shfl_xor(v, off));
  return v;
}

// ---- RELAXED agent-scope accessors: compile to sc1 loads/stores that are
// coherent at the Infinity-Cache point WITHOUT emitting buffer_inv /
// buffer_wbl2 (the full-L2 maintenance ops that acquire/release fences cost).
__device__ __forceinline__ uint ald(const uint* p) {
  return __hip_atomic_load(p, __ATOMIC_RELAXED, __HIP_MEMORY_SCOPE_AGENT);
}
__device__ __forceinline__ void ast(uint* p, uint v) {
  __hip_atomic_store(p, v, __ATOMIC_RELAXED, __HIP_MEMORY_SCOPE_AGENT);
}
__device__ __forceinline__ float aldf(const float* p) {
  return __hip_atomic_load(p, __ATOMIC_RELAXED, __HIP_MEMORY_SCOPE_AGENT);
}
__device__ __forceinline__ void astf(float* p, float v) {
  __hip_atomic_store(p, v, __ATOMIC_RELAXED, __HIP_MEMORY_SCOPE_AGENT);
}
__device__ __forceinline__ int aldi(const int* p) {
  return __hip_atomic_load(p, __ATOMIC_RELAXED, __HIP_MEMORY_SCOPE_AGENT);
}
__device__ __forceinline__ void asti(int* p, int v) {
  __hip_atomic_store(p, v, __ATOMIC_RELAXED, __HIP_MEMORY_SCOPE_AGENT);
}
// Drain this thread's outstanding vmem (stores ACK'd at coherence point).
__device__ __forceinline__ void fence_vm() {
  asm volatile("s_waitcnt vmcnt(0)" ::: "memory");
}

// Fence-free grid barrier. Data-before-flag ordering: __syncthreads() drains
// all the block's vmem (compiler emits s_waitcnt vmcnt(0) before s_barrier),
// so every sc1 data store is IC-visible before the arrival flag is stored.
__device__ __forceinline__ void gbar(uint* arrive, uint* done, uint r) {
  __syncthreads();
  if (blockIdx.x == 0) {
    const int tid = threadIdx.x;
    if (tid >= 1 && tid < NBLK) {
      const uint* slot = arrive + tid * 32;
      while (ald(slot) < r) __builtin_amdgcn_s_sleep(1);
    }
    __syncthreads();
    if (tid < 32) ast(done + tid * 32, r);
  } else {
    if (threadIdx.x == 0) {
      fence_vm();
      ast(arrive + blockIdx.x * 32, r);
      const uint* dl = done + (blockIdx.x >> 3) * 32;
      while (ald(dl) < r) __builtin_amdgcn_s_sleep(1);
    }
    __syncthreads();
  }
}

// fp32 -> bf16 (RNE) converter, run each launch into d_ws
__global__ void conv_kernel(const float* __restrict__ W,
                            ushort* __restrict__ o, int n4) {
  int i = blockIdx.x * blockDim.x + threadIdx.x;
  int stride = gridDim.x * blockDim.x;
  for (; i < n4; i += stride) {
    float4 f = ((const float4*)W)[i];
    ushort4 u;
    uint b;
    b = __float_as_uint(f.x); u.x = (ushort)((b + 0x7fffu + ((b >> 16) & 1u)) >> 16);
    b = __float_as_uint(f.y); u.y = (ushort)((b + 0x7fffu + ((b >> 16) & 1u)) >> 16);
    b = __float_as_uint(f.z); u.z = (ushort)((b + 0x7fffu + ((b >> 16) & 1u)) >> 16);
    b = __float_as_uint(f.w); u.w = (ushort)((b + 0x7fffu + ((b >> 16) & 1u)) >> 16);
    ((ushort4*)o)[i] = u;
  }
}

template <int BF>
__global__ void __launch_bounds__(NTHR)
seq2seq_kernel(const int* __restrict__ source, int S,
               const int* __restrict__ n_steps_p, const int* __restrict__ start_tok_p,
               const float* __restrict__ Wemb_enc,
               const float* __restrict__ W_ih_e, const float* __restrict__ W_hh_e,
               const float* __restrict__ b_ih_e, const float* __restrict__ b_hh_e,
               const float* __restrict__ Wemb_dec,
               const float* __restrict__ W_ih_d, const float* __restrict__ W_hh_d,
               const float* __restrict__ b_ih_d, const float* __restrict__ b_hh_d,
               const float* __restrict__ W_out, const float* __restrict__ b_out,
               const ushort* __restrict__ Wbf,
               float* __restrict__ out,
               float* gates, float* psoft, float* pargv, int* pargi, float* psum,
               uint* arrive, uint* done)
{
  const int tid  = threadIdx.x;
  const int blk  = blockIdx.x;
  const int wave = tid >> 6;
  const int lane = tid & 63;
  const int l32  = lane & 31;
  const int rh   = lane >> 5;   // which of the wave's 2 rows

  __shared__ float4 x4[2][HDIM / 4];
  __shared__ float4 h4[HDIM / 4];
  __shared__ float  c_lds[HDIM];
  __shared__ float  e_lds[200];
  __shared__ float  red_v[NWAVE];
  __shared__ int    red_i[NWAVE];
  __shared__ float  red_s[NWAVE];
  __shared__ float  red_m[NWAVE];
  __shared__ float  red_v2[NWAVE];
  __shared__ int    red_i2[NWAVE];
  __shared__ int    sh_tok;
  __shared__ float  sh_lmax, sh_S;

  float* h_s = (float*)h4;

  for (int j = tid; j < HDIM; j += NTHR) { h_s[j] = 0.f; c_lds[j] = 0.f; }

  // ---- pin encoder LSTM weight slice in VGPRs (2 rows/wave, 16 f4/thread) ----
  const int r_e = blk * 16 + wave * 2 + rh;
  float4 wie[8], whe[8];
  {
    const float4* pie = (const float4*)(W_ih_e + (size_t)r_e * HDIM);
    const float4* phe = (const float4*)(W_hh_e + (size_t)r_e * HDIM);
#pragma unroll
    for (int c = 0; c < 8; ++c) { wie[c] = pie[l32 + 32 * c]; whe[c] = phe[l32 + 32 * c]; }
  }
  const float bse = b_ih_e[r_e] + b_hh_e[r_e];

  if (tid < 256)
    x4[0][tid] = ((const float4*)(Wemb_enc + (size_t)source[0] * HDIM))[tid];
  __syncthreads();

  uint rnd = 0;
  int gstep = 0, xb = 0;

  // ================= encoder =================
  for (int t = 0; t < S; ++t) {
    float4 pf;
    const bool havepf = (t + 1 < S) && (tid < 256);
    if (havepf)
      pf = ((const float4*)(Wemb_enc + (size_t)source[t + 1] * HDIM))[tid];

    float g = bse;
    const float4* xf = (const float4*)&x4[xb][0];
#pragma unroll
    for (int c = 0; c < 8; ++c) {
      g += dot4(wie[c], xf[l32 + 32 * c]);
      g += dot4(whe[c], h4[l32 + 32 * c]);
    }
    g = wred32(g);
    float* gcur = gates + (gstep & 1) * 4096;
    if (l32 == 0) astf(&gcur[r_e], g);

    gbar(arrive, done, ++rnd);

#pragma unroll
    for (int q = 0; q < 2; ++q) {
      int j = tid + q * NTHR;
      float ig = aldf(&gcur[j]),        fg = aldf(&gcur[j + 1024]);
      float gv = aldf(&gcur[j + 2048]), og = aldf(&gcur[j + 3072]);
      float ii = 1.f / (1.f + expf(-ig));
      float ff = 1.f / (1.f + expf(-fg));
      float gt = tanhf(gv);
      float oo = 1.f / (1.f + expf(-og));
      float cc = ff * c_lds[j] + ii * gt;
      c_lds[j] = cc;
      h_s[j]   = oo * tanhf(cc);
    }
    if (havepf) x4[xb ^ 1][tid] = pf;
    __syncthreads();
    xb ^= 1;
    ++gstep;
  }

  // ================= decoder =================
  const int nsteps = n_steps_p[0];
  const int r_d = blk * 16 + wave * 2 + rh;
  const float bsd = b_ih_d[r_d] + b_hh_d[r_d];
  const float4* pid = (const float4*)(W_ih_d + (size_t)r_d * HDIM);
  const float4* phd = (const float4*)(W_hh_d + (size_t)r_d * HDIM);

  const int start = blk * 196 + (blk < 81 ? blk : 81);
  const int count = 196 + (blk < 81 ? 1 : 0);

  float4 pfx;
  if (tid < 256)
    pfx = ((const float4*)(Wemb_dec + (size_t)start_tok_p[0] * HDIM))[tid];

  for (int t = 0; t < nsteps; ++t) {
    if (tid < 256) x4[0][tid] = pfx;
    __syncthreads();

    // ---- LSTM gates (streamed; 16 f4 loads in flight; 1 row per half-wave) ----
    {
      const float4* xf = (const float4*)&x4[0][0];
      float g = bsd;
#pragma unroll
      for (int c = 0; c < 8; ++c) {
        g += dot4(pid[l32 + 32 * c], xf[l32 + 32 * c]);
        g += dot4(phd[l32 + 32 * c], h4[l32 + 32 * c]);
      }
      g = wred32(g);
      float* gcur = gates + (gstep & 1) * 4096;
      if (l32 == 0) astf(&gcur[r_d], g);
    }
    gbar(arrive, done, ++rnd);  // (A)
    {
      const float* gcur = gates + (gstep & 1) * 4096;
#pragma unroll
      for (int q = 0; q < 2; ++q) {
        int j = tid + q * NTHR;
        float ig = aldf(&gcur[j]),        fg = aldf(&gcur[j + 1024]);
        float gv = aldf(&gcur[j + 2048]), og = aldf(&gcur[j + 3072]);
        float ii = 1.f / (1.f + expf(-ig));
        float ff = 1.f / (1.f + expf(-fg));
        float gt = tanhf(gv);
        float oo = 1.f / (1.f + expf(-og));
        float cc = ff * c_lds[j] + ii * gt;
        c_lds[j] = cc;
        h_s[j]   = oo * tanhf(cc);
      }
    }
    ++gstep;
    __syncthreads();

    // ---- logit scan ----
    if (BF) {
      // h slice pinned in registers: lane covers elements [8l,8l+8) and [512+8l,...)
      float4 ha0 = h4[2 * lane], ha1 = h4[2 * lane + 1];
      float4 hb0 = h4[128 + 2 * lane], hb1 = h4[128 + 2 * lane + 1];
      for (int jb = wave * 4; jb < count; jb += NWAVE * 4) {
        int n_ = count - jb;
        const ushort* bb = Wbf + (size_t)(start + jb) * HDIM;
        const uint4* r0 = (const uint4*)bb;
        const uint4* r1 = (const uint4*)(bb + (n_ > 1 ? HDIM : 0));
        const uint4* r2 = (const uint4*)(bb + (n_ > 2 ? 2 * HDIM : 0));
        const uint4* r3 = (const uint4*)(bb + (n_ > 3 ? 3 * HDIM : 0));
        uint4 u0 = r0[lane], u1 = r0[lane + 64];
        uint4 u2 = r1[lane], u3 = r1[lane + 64];
        uint4 u4 = r2[lane], u5 = r2[lane + 64];
        uint4 u6 = r3[lane], u7 = r3[lane + 64];
        float a0 = dot8(u0, ha0, ha1) + dot8(u1, hb0, hb1);
        float a1 = dot8(u2, ha0, ha1) + dot8(u3, hb0, hb1);
        float a2 = dot8(u4, ha0, ha1) + dot8(u5, hb0, hb1);
        float a3 = dot8(u6, ha0, ha1) + dot8(u7, hb0, hb1);
        a0 = wred64(a0); a1 = wred64(a1); a2 = wred64(a2); a3 = wred64(a3);
        if (lane == 0) {
          e_lds[jb] = a0 + b_out[start + jb];
          if (n_ > 1) e_lds[jb + 1] = a1 + b_out[start + jb + 1];
          if (n_ > 2) e_lds[jb + 2] = a2 + b_out[start + jb + 2];
          if (n_ > 3) e_lds[jb + 3] = a3 + b_out[start + jb + 3];
        }
      }
    } else {
      for (int jb = wave * 4; jb < count; jb += NWAVE * 4) {
        int n_ = count - jb;
        const float4* r0 = (const float4*)(W_out + (size_t)(start + jb) * HDIM);
        const float4* r1 = (const float4*)(W_out + (size_t)(start + jb + (n_ > 1 ? 1 : 0)) * HDIM);
        const float4* r2 = (const float4*)(W_out + (size_t)(start + jb + (n_ > 2 ? 2 : 0)) * HDIM);
        const float4* r3 = (const float4*)(W_out + (size_t)(start + jb + (n_ > 3 ? 3 : 0)) * HDIM);
        float a0 = 0.f, a1 = 0.f, a2 = 0.f, a3 = 0.f;
#pragma unroll
        for (int c = 0; c < 4; ++c) {
          float4 hh = h4[lane + 64 * c];
          a0 += dot4(r0[lane + 64 * c], hh);
          a1 += dot4(r1[lane + 64 * c], hh);
          a2 += dot4(r2[lane + 64 * c], hh);
          a3 += dot4(r3[lane + 64 * c], hh);
        }
        a0 = wred64(a0); a1 = wred64(a1); a2 = wred64(a2); a3 = wred64(a3);
        if (lane == 0) {
          e_lds[jb] = a0 + b_out[start + jb];
          if (n_ > 1) e_lds[jb + 1] = a1 + b_out[start + jb + 1];
          if (n_ > 2) e_lds[jb + 2] = a2 + b_out[start + jb + 2];
          if (n_ > 3) e_lds[jb + 3] = a3 + b_out[start + jb + 3];
        }
      }
    }
    __syncthreads();

    // ---- block-local bf16 max/argmax (np.argmax tie-break: lowest index) ----
    float m_soft; int i_soft;
    {
      float v = -INFINITY; int idx = 0x7fffffff;
      if (tid < count) { v = e_lds[tid]; idx = start + tid; }
      wmax64(v, idx);
      if (lane == 0) { red_v[wave] = v; red_i[wave] = idx; }
    }
    __syncthreads();
    {
      float v = red_v[0]; int idx = red_i[0];
#pragma unroll
      for (int w = 1; w < NWAVE; ++w) {
        float v2 = red_v[w]; int i2 = red_i[w];
        if (v2 > v || (v2 == v && i2 < idx)) { v = v2; idx = i2; }
      }
      m_soft = v; i_soft = idx;
    }

    // ---- exp partial (own value in register) + sum ----
    float pe = (tid < count) ? expf(e_lds[tid] - m_soft) : 0.f;
    {
      float ls = wred64(pe);
      if (lane == 0) red_s[wave] = ls;
    }

    // ---- fp32 rescore of near-max candidates (BF path; argmax-exact) ----
    float m_arg = m_soft; int i_arg = i_soft;
    if (BF) {
      float bv = -INFINITY; int bi = 0x7fffffff;
      for (int j = wave; j < count; j += NWAVE) {   // j wave-uniform
        if (e_lds[j] >= m_soft - DELTA) {
          const float4* w = (const float4*)(W_out + (size_t)(start + j) * HDIM);
          float a = 0.f;
#pragma unroll
          for (int c = 0; c < 4; ++c) a += dot4(w[lane + 64 * c], h4[lane + 64 * c]);
          a = wred64(a) + b_out[start + j];
          if (a > bv) { bv = a; bi = start + j; }   // ascending j => min idx on ties
        }
      }
      if (lane == 0) { red_v2[wave] = bv; red_i2[wave] = bi; }
    }
    __syncthreads();
    float lsum = 0.f;
#pragma unroll
    for (int w = 0; w < NWAVE; ++w) lsum += red_s[w];
    if (BF) {
      float v = red_v2[0]; int idx = red_i2[0];
#pragma unroll
      for (int w = 1; w < NWAVE; ++w) {
        float v2 = red_v2[w]; int i2 = red_i2[w];
        if (v2 > v || (v2 == v && i2 < idx)) { v = v2; idx = i2; }
      }
      m_arg = v; i_arg = idx;
    }

    if (tid == 0) {
      astf(&psoft[blk], m_soft); astf(&pargv[blk], m_arg);
      asti(&pargi[blk], i_arg);  astf(&psum[blk], lsum);
    }

    // ---- barrier B with payload: block0 reduces once, publishes result ----
    ++rnd;
    __syncthreads();   // drains vmem: partial stores IC-visible before arrival
    int tokn; float lmax, Ssum;
    if (blk == 0) {
      if (tid >= 1 && tid < NBLK) {
        const uint* slot = arrive + tid * 32;
        while (ald(slot) < rnd) __builtin_amdgcn_s_sleep(1);
      }
      __syncthreads();
      float v = -INFINITY, m = -INFINITY, mysum = 0.f, myms = 0.f;
      int idx = 0x7fffffff;
      if (tid < NBLK) {
        v     = aldf(&pargv[tid]);
        idx   = aldi(&pargi[tid]);
        m     = aldf(&psoft[tid]);
        mysum = aldf(&psum[tid]);
        myms  = m;
      }
      wmax64(v, idx);
      float mm = wvmax64(m);
      if (lane == 0 && wave < 4) { red_v[wave] = v; red_i[wave] = idx; red_m[wave] = mm; }
      __syncthreads();
      {
        float vv = red_v[0]; int ii2 = red_i[0]; float mmax = red_m[0];
#pragma unroll
        for (int w = 1; w < 4; ++w) {
          float v2 = red_v[w]; int i2 = red_i[w];
          if (v2 > vv || (v2 == vv && i2 < ii2)) { vv = v2; ii2 = i2; }
          mmax = fmaxf(mmax, red_m[w]);
        }
        tokn = ii2; lmax = mmax;
      }
      {
        float s = (tid < NBLK) ? mysum * expf(myms - lmax) : 0.f;
        s = wred64(s);
        if (lane == 0 && wave < 4) red_s[wave] = s;
      }
      __syncthreads();
      Ssum = red_s[0] + red_s[1] + red_s[2] + red_s[3];
      if (tid < 32) {
        uint* dl = done + tid * 32;
        ast(dl + 1, (uint)tokn);
        ast(dl + 2, __float_as_uint(lmax));
        ast(dl + 3, __float_as_uint(Ssum));
        fence_vm();                 // payload at IC before flag
        ast(dl, rnd);
      }
    } else {
      if (tid == 0) {
        fence_vm();
        ast(arrive + blk * 32, rnd);
        const uint* dl = done + (blk >> 3) * 32;
        while (ald(dl) < rnd) __builtin_amdgcn_s_sleep(1);
        sh_tok  = (int)ald(dl + 1);
        sh_lmax = __uint_as_float(ald(dl + 2));
        sh_S    = __uint_as_float(ald(dl + 3));
      }
      __syncthreads();
      tokn = sh_tok; lmax = sh_lmax; Ssum = sh_S;
    }

    // prefetch next token's embedding row (hides under the prob stores)
    if (tid < 256)
      pfx = ((const float4*)(Wemb_dec + (size_t)tokn * HDIM))[tid];

    float scale = expf(m_soft - lmax) / Ssum;
    if (tid < count)
      out[(size_t)nsteps + (size_t)t * VDIM + start + tid] = pe * scale;
    if (blk == 0 && tid == 0) out[t] = (float)tokn;
  }
}

extern "C" void kernel_launch(void* const* d_in, const int* in_sizes, int n_in,
                              void* d_out, int out_size, void* d_ws, size_t ws_size,
                              hipStream_t stream) {
  const int*   source      = (const int*)d_in[0];
  const int*   n_steps_p   = (const int*)d_in[1];
  const int*   start_tok_p = (const int*)d_in[2];
  const float* Wemb_enc    = (const float*)d_in[3];
  const float* W_ih_e      = (const float*)d_in[4];
  const float* W_hh_e      = (const float*)d_in[5];
  const float* b_ih_e      = (const float*)d_in[6];
  const float* b_hh_e      = (const float*)d_in[7];
  const float* Wemb_dec    = (const float*)d_in[8];
  const float* W_ih_d      = (const float*)d_in[9];
  const float* W_hh_d      = (const float*)d_in[10];
  const float* b_ih_d      = (const float*)d_in[11];
  const float* b_hh_d      = (const float*)d_in[12];
  const float* W_out       = (const float*)d_in[13];
  const float* b_out       = (const float*)d_in[14];
  float*       out         = (float*)d_out;
  int          S           = in_sizes[0];

  char* ws = (char*)d_ws;
  float*  gates  = (float*)(ws + WS_GATES);
  float*  psoft  = (float*)(ws + WS_PSOFT);
  float*  pargv  = (float*)(ws + WS_PARGV);
  int*    pargi  = (int*)  (ws + WS_PARGI);
  float*  psum   = (float*)(ws + WS_PSUM);
  uint*   arrive = (uint*) (ws + WS_ARRIVE);
  uint*   done   = (uint*) (ws + WS_DONE);
  ushort* Wbf    = (ushort*)(ws + WS_WBF);

  bool use_bf = ws_size >= (size_t)WS_WBF + WBF_BYTES;

  // zero barrier slots/done (+partials) every launch -> replay-deterministic
  hipMemsetAsync(ws + WS_ZOFF, 0, WS_ZLEN, stream);

  if (use_bf)
    conv_kernel<<<2048, 256, 0, stream>>>(W_out, Wbf, VDIM * HDIM / 4);

  void* args[] = { &source, &S, &n_steps_p, &start_tok_p, &Wemb_enc,
                   &W_ih_e, &W_hh_e, &b_ih_e, &b_hh_e, &Wemb_dec,
                   &W_ih_d, &W_hh_d, &b_ih_d, &b_hh_d, &W_out, &b_out,
                   &Wbf, &out, &gates, &psoft, &pargv, &pargi, &psum,
                   &arrive, &done };

  void* kfn = use_bf ? (void*)seq2seq_kernel<1> : (void*)seq2seq_kernel<0>;
  hipLaunchCooperativeKernel(kfn, dim3(NBLK), dim3(NTHR), args, 0, stream);
}

// Round 6
// 5090.721 us; speedup vs baseline: 5.0222x; 1.2992x over previous
//
#include <hip/hip_runtime.h>
#include <math.h>

#define HDIM  1024
#define VDIM  50257
#define NBLK  256
#define NTHR  1024
#define NWAVE 16

typedef unsigned int uint;

// ---------------- ws layout ----------------
#define WS_GATES   0         // 2*4096 f32 = 32 KiB (double-buffered gates)
#define WS_PSOFT   32768     // 256 f32  block fp8-softmax max
#define WS_PARGV   33792     // 256 f32  block argmax value (fp32-exact)
#define WS_PARGI   34816     // 256 i32  block argmax index
#define WS_PSUM    35840     // 256 f32  block exp-sum
#define WS_ARRIVE  36864     // 256 slots * 128 B (per-block arrival)
#define WS_DONE    69632     // 32 lines * 128 B: [0]=round [1]=tok [2]=lmax [3]=Ssum
#define WS_ZOFF    32768
#define WS_ZLEN    40960
#define WS_W8      131072    // fp8 e4m3 W_out (optional)
#define W8_BYTES   ((size_t)VDIM * HDIM)

#if __has_builtin(__builtin_amdgcn_cvt_pk_f32_fp8) && __has_builtin(__builtin_amdgcn_cvt_pk_fp8_f32)
#define FP8_HW 1
#else
#define FP8_HW 0
#endif

__device__ __forceinline__ float dot4(float4 a, float4 b) {
  return a.x * b.x + a.y * b.y + a.z * b.z + a.w * b.w;
}

#if !FP8_HW
// manual e4m3fn decode (normals + subnormals; encoder never emits NaN)
__device__ __forceinline__ float fp8d(uint b) {
  uint em = b & 0x7fu;
  float m;
  if (em >= 8u) m = __uint_as_float(((((em >> 3) + 120u) << 23) | ((em & 7u) << 20)));
  else          m = (float)em * 0.001953125f;   // m * 2^-9
  return (b & 0x80u) ? -m : m;
}
__device__ __forceinline__ uint fp8e(float x) {
  uint s = (__float_as_uint(x) >> 24) & 0x80u;
  float ax = fabsf(x);
  uint r;
  if (ax < 0.015625f) {
    r = (uint)rintf(ax * 512.f);                 // RNE subnormal; 8 -> 0x08 == 2^-6
  } else {
    uint b = __float_as_uint(ax);
    b += 0x7ffffu + ((b >> 20) & 1u);            // RNE into 3-bit mantissa
    int  e8 = (int)(b >> 23) - 127 + 7;
    uint m8 = (b >> 20) & 7u;
    if (e8 >= 16 || (e8 == 15 && m8 == 7u)) { e8 = 15; m8 = 6u; }  // clamp 448
    r = ((uint)e8 << 3) | m8;
  }
  return r | s;
}
#endif

// dot of 16 packed fp8 (uint4) with h[16l..16l+16) held as 4 float4
__device__ __forceinline__ float dot16_fp8(uint4 u, float4 h0, float4 h1,
                                           float4 h2, float4 h3) {
#if FP8_HW
  float s = 0.f;
  { auto a = __builtin_amdgcn_cvt_pk_f32_fp8((int)u.x, false);
    auto b = __builtin_amdgcn_cvt_pk_f32_fp8((int)u.x, true);
    s += a[0] * h0.x + a[1] * h0.y + b[0] * h0.z + b[1] * h0.w; }
  { auto a = __builtin_amdgcn_cvt_pk_f32_fp8((int)u.y, false);
    auto b = __builtin_amdgcn_cvt_pk_f32_fp8((int)u.y, true);
    s += a[0] * h1.x + a[1] * h1.y + b[0] * h1.z + b[1] * h1.w; }
  { auto a = __builtin_amdgcn_cvt_pk_f32_fp8((int)u.z, false);
    auto b = __builtin_amdgcn_cvt_pk_f32_fp8((int)u.z, true);
    s += a[0] * h2.x + a[1] * h2.y + b[0] * h2.z + b[1] * h2.w; }
  { auto a = __builtin_amdgcn_cvt_pk_f32_fp8((int)u.w, false);
    auto b = __builtin_amdgcn_cvt_pk_f32_fp8((int)u.w, true);
    s += a[0] * h3.x + a[1] * h3.y + b[0] * h3.z + b[1] * h3.w; }
  return s;
#else
  float s = 0.f;
  s += fp8d(u.x & 255u) * h0.x + fp8d((u.x >> 8) & 255u) * h0.y +
       fp8d((u.x >> 16) & 255u) * h0.z + fp8d(u.x >> 24) * h0.w;
  s += fp8d(u.y & 255u) * h1.x + fp8d((u.y >> 8) & 255u) * h1.y +
       fp8d((u.y >> 16) & 255u) * h1.z + fp8d(u.y >> 24) * h1.w;
  s += fp8d(u.z & 255u) * h2.x + fp8d((u.z >> 8) & 255u) * h2.y +
       fp8d((u.z >> 16) & 255u) * h2.z + fp8d(u.z >> 24) * h2.w;
  s += fp8d(u.w & 255u) * h3.x + fp8d((u.w >> 8) & 255u) * h3.y +
       fp8d((u.w >> 16) & 255u) * h3.z + fp8d(u.w >> 24) * h3.w;
  return s;
#endif
}

__device__ __forceinline__ float wred64(float v) {
  v += __shfl_xor(v, 32); v += __shfl_xor(v, 16); v += __shfl_xor(v, 8);
  v += __shfl_xor(v, 4);  v += __shfl_xor(v, 2);  v += __shfl_xor(v, 1);
  return v;
}

__device__ __forceinline__ void wmax64(float& v, int& i) {
#pragma unroll
  for (int off = 32; off > 0; off >>= 1) {
    float v2 = __shfl_xor(v, off);
    int   i2 = __shfl_xor(i, off);
    if (v2 > v || (v2 == v && i2 < i)) { v = v2; i = i2; }
  }
}

__device__ __forceinline__ float wvmax64(float v) {
#pragma unroll
  for (int off = 32; off > 0; off >>= 1) v = fmaxf(v, __shfl_xor(v, off));
  return v;
}

// ---- RELAXED agent-scope accessors (sc1, IC-coherent, NO buffer_inv/wbl2) ----
__device__ __forceinline__ uint ald(const uint* p) {
  return __hip_atomic_load(p, __ATOMIC_RELAXED, __HIP_MEMORY_SCOPE_AGENT);
}
__device__ __forceinline__ void ast(uint* p, uint v) {
  __hip_atomic_store(p, v, __ATOMIC_RELAXED, __HIP_MEMORY_SCOPE_AGENT);
}
__device__ __forceinline__ float aldf(const float* p) {
  return __hip_atomic_load(p, __ATOMIC_RELAXED, __HIP_MEMORY_SCOPE_AGENT);
}
__device__ __forceinline__ void astf(float* p, float v) {
  __hip_atomic_store(p, v, __ATOMIC_RELAXED, __HIP_MEMORY_SCOPE_AGENT);
}
__device__ __forceinline__ int aldi(const int* p) {
  return __hip_atomic_load(p, __ATOMIC_RELAXED, __HIP_MEMORY_SCOPE_AGENT);
}
__device__ __forceinline__ void asti(int* p, int v) {
  __hip_atomic_store(p, v, __ATOMIC_RELAXED, __HIP_MEMORY_SCOPE_AGENT);
}
__device__ __forceinline__ void fence_vm() {
  asm volatile("s_waitcnt vmcnt(0)" ::: "memory");
}

// Fence-free grid barrier (proven R5). __syncthreads drains block vmem before
// the arrival flag; payloads are published before the done flag via fence_vm.
__device__ __forceinline__ void gbar(uint* arrive, uint* done, uint r) {
  __syncthreads();
  if (blockIdx.x == 0) {
    const int tid = threadIdx.x;
    if (tid >= 1 && tid < NBLK) {
      const uint* slot = arrive + tid * 32;
      while (ald(slot) < r) __builtin_amdgcn_s_sleep(1);
    }
    __syncthreads();
    if (tid < 32) ast(done + tid * 32, r);
  } else {
    if (threadIdx.x == 0) {
      fence_vm();
      ast(arrive + blockIdx.x * 32, r);
      const uint* dl = done + (blockIdx.x >> 3) * 32;
      while (ald(dl) < r) __builtin_amdgcn_s_sleep(1);
    }
    __syncthreads();
  }
}

// fp32 -> fp8 e4m3 (RNE) converter, each launch into d_ws
__global__ void conv8_kernel(const float* __restrict__ W,
                             uint4* __restrict__ o, int n16) {
  int i = blockIdx.x * blockDim.x + threadIdx.x;
  int stride = gridDim.x * blockDim.x;
  const float4* W4 = (const float4*)W;
  for (; i < n16; i += stride) {
    float4 f0 = W4[4 * i], f1 = W4[4 * i + 1], f2 = W4[4 * i + 2], f3 = W4[4 * i + 3];
    uint4 u;
#if FP8_HW
    int p;
    p = __builtin_amdgcn_cvt_pk_fp8_f32(f0.x, f0.y, 0, false);
    p = __builtin_amdgcn_cvt_pk_fp8_f32(f0.z, f0.w, p, true);  u.x = (uint)p;
    p = __builtin_amdgcn_cvt_pk_fp8_f32(f1.x, f1.y, 0, false);
    p = __builtin_amdgcn_cvt_pk_fp8_f32(f1.z, f1.w, p, true);  u.y = (uint)p;
    p = __builtin_amdgcn_cvt_pk_fp8_f32(f2.x, f2.y, 0, false);
    p = __builtin_amdgcn_cvt_pk_fp8_f32(f2.z, f2.w, p, true);  u.z = (uint)p;
    p = __builtin_amdgcn_cvt_pk_fp8_f32(f3.x, f3.y, 0, false);
    p = __builtin_amdgcn_cvt_pk_fp8_f32(f3.z, f3.w, p, true);  u.w = (uint)p;
#else
    u.x = fp8e(f0.x) | (fp8e(f0.y) << 8) | (fp8e(f0.z) << 16) | (fp8e(f0.w) << 24);
    u.y = fp8e(f1.x) | (fp8e(f1.y) << 8) | (fp8e(f1.z) << 16) | (fp8e(f1.w) << 24);
    u.z = fp8e(f2.x) | (fp8e(f2.y) << 8) | (fp8e(f2.z) << 16) | (fp8e(f2.w) << 24);
    u.w = fp8e(f3.x) | (fp8e(f3.y) << 8) | (fp8e(f3.z) << 16) | (fp8e(f3.w) << 24);
#endif
    o[i] = u;
  }
}

template <int Q8>
__global__ void __launch_bounds__(NTHR, 4)
seq2seq_kernel(const int* __restrict__ source, int S,
               const int* __restrict__ n_steps_p, const int* __restrict__ start_tok_p,
               const float* __restrict__ Wemb_enc,
               const float* __restrict__ W_ih_e, const float* __restrict__ W_hh_e,
               const float* __restrict__ b_ih_e, const float* __restrict__ b_hh_e,
               const float* __restrict__ Wemb_dec,
               const float* __restrict__ W_ih_d, const float* __restrict__ W_hh_d,
               const float* __restrict__ b_ih_d, const float* __restrict__ b_hh_d,
               const float* __restrict__ W_out, const float* __restrict__ b_out,
               const uint4* __restrict__ W8,
               float* __restrict__ out,
               float* gates, float* psoft, float* pargv, int* pargi, float* psum,
               uint* arrive, uint* done)
{
  const int tid  = threadIdx.x;
  const int blk  = blockIdx.x;
  const int wave = tid >> 6;
  const int lane = tid & 63;

  __shared__ float4 x4[2][HDIM / 4];
  __shared__ float4 h4[HDIM / 4];
  __shared__ float  hscan[HDIM];      // XOR-swizzled copy for fp8 scan
  __shared__ float  c_lds[HDIM];
  __shared__ float  e_lds[200];
  __shared__ float  red_v[NWAVE];
  __shared__ int    red_i[NWAVE];
  __shared__ float  red_s[NWAVE];
  __shared__ float  red_m[NWAVE];
  __shared__ float  red_n[NWAVE];
  __shared__ float  red_v2[NWAVE];
  __shared__ int    red_i2[NWAVE];
  __shared__ int    sh_tok;
  __shared__ float  sh_lmax, sh_S;

  float* h_s = (float*)h4;

  h_s[tid] = 0.f;
  c_lds[tid] = 0.f;

  // ---- pin encoder LSTM weight slice (1 row/wave, 8 f4/thread = 32 VGPR) ----
  const int r_e = blk * NWAVE + wave;
  float4 wie[4], whe[4];
  {
    const float4* pie = (const float4*)(W_ih_e + (size_t)r_e * HDIM);
    const float4* phe = (const float4*)(W_hh_e + (size_t)r_e * HDIM);
#pragma unroll
    for (int c = 0; c < 4; ++c) {
      wie[c] = pie[lane + 64 * c];
      whe[c] = phe[lane + 64 * c];
    }
  }
  const float bse = b_ih_e[r_e] + b_hh_e[r_e];

  if (tid < 256)
    x4[0][tid] = ((const float4*)(Wemb_enc + (size_t)source[0] * HDIM))[tid];
  __syncthreads();

  uint rnd = 0;
  int gstep = 0, xb = 0;

  // ================= encoder =================
  for (int t = 0; t < S; ++t) {
    float4 pf;
    const bool havepf = (t + 1 < S) && (tid < 256);
    if (havepf)
      pf = ((const float4*)(Wemb_enc + (size_t)source[t + 1] * HDIM))[tid];

    float g = bse;
    const float4* xf = (const float4*)&x4[xb][0];
#pragma unroll
    for (int c = 0; c < 4; ++c) {
      g += dot4(wie[c], xf[lane + 64 * c]);
      g += dot4(whe[c], h4[lane + 64 * c]);
    }
    g = wred64(g);
    float* gcur = gates + (gstep & 1) * 4096;
    if (lane == 0) astf(&gcur[r_e], g);

    gbar(arrive, done, ++rnd);

    {
      float ig = aldf(&gcur[tid]),        fg = aldf(&gcur[tid + 1024]);
      float gv = aldf(&gcur[tid + 2048]), og = aldf(&gcur[tid + 3072]);
      float ii = 1.f / (1.f + expf(-ig));
      float ff = 1.f / (1.f + expf(-fg));
      float gt = tanhf(gv);
      float oo = 1.f / (1.f + expf(-og));
      float cc = ff * c_lds[tid] + ii * gt;
      c_lds[tid] = cc;
      h_s[tid]   = oo * tanhf(cc);
    }
    if (havepf) x4[xb ^ 1][tid] = pf;
    __syncthreads();
    xb ^= 1;
    ++gstep;
  }

  // ================= decoder =================
  const int nsteps = n_steps_p[0];
  const int r_d = blk * NWAVE + wave;
  const float bsd = b_ih_d[r_d] + b_hh_d[r_d];

  // ---- pin decoder LSTM weight slice in VGPRs (32 VGPR/thread) ----
  float4 wid[4], whd[4];
  {
    const float4* pid = (const float4*)(W_ih_d + (size_t)r_d * HDIM);
    const float4* phd = (const float4*)(W_hh_d + (size_t)r_d * HDIM);
#pragma unroll
    for (int c = 0; c < 4; ++c) {
      wid[c] = pid[lane + 64 * c];
      whd[c] = phd[lane + 64 * c];
    }
  }

  const int start = blk * 196 + (blk < 81 ? blk : 81);
  const int count = 196 + (blk < 81 ? 1 : 0);

  float4 pfx;
  if (tid < 256)
    pfx = ((const float4*)(Wemb_dec + (size_t)start_tok_p[0] * HDIM))[tid];

  for (int t = 0; t < nsteps; ++t) {
    if (tid < 256) x4[0][tid] = pfx;
    __syncthreads();

    // ---- LSTM gates (weights in registers) ----
    {
      const float4* xf = (const float4*)&x4[0][0];
      float g = bsd;
#pragma unroll
      for (int c = 0; c < 4; ++c) {
        g += dot4(wid[c], xf[lane + 64 * c]);
        g += dot4(whd[c], h4[lane + 64 * c]);
      }
      g = wred64(g);
      float* gcur = gates + (gstep & 1) * 4096;
      if (lane == 0) astf(&gcur[r_d], g);
    }
    gbar(arrive, done, ++rnd);  // (A)
    {
      const float* gcur = gates + (gstep & 1) * 4096;
      float ig = aldf(&gcur[tid]),        fg = aldf(&gcur[tid + 1024]);
      float gv = aldf(&gcur[tid + 2048]), og = aldf(&gcur[tid + 3072]);
      float ii = 1.f / (1.f + expf(-ig));
      float ff = 1.f / (1.f + expf(-fg));
      float gt = tanhf(gv);
      float oo = 1.f / (1.f + expf(-og));
      float cc = ff * c_lds[tid] + ii * gt;
      c_lds[tid] = cc;
      float hv = oo * tanhf(cc);
      h_s[tid] = hv;
      // swizzled copy: element e -> dword 4*(c ^ ((c>>3)&7)) + (e&3), c=e>>2
      hscan[((((tid >> 2) ^ ((tid >> 5) & 7)) << 2) | (tid & 3))] = hv;
      // ||h||^2 partial (for adaptive rescore window)
      float h2 = wred64(hv * hv);
      if (lane == 0) red_n[wave] = h2;
    }
    ++gstep;
    __syncthreads();

    // ---- logit scan ----
    if (Q8) {
      // h slice in registers: lane covers elements [16l, 16l+16)
      const float4* hs4 = (const float4*)hscan;
      const int c0 = 4 * lane;
      float4 h0 = hs4[(c0 + 0) ^ (((c0 + 0) >> 3) & 7)];
      float4 h1 = hs4[(c0 + 1) ^ (((c0 + 1) >> 3) & 7)];
      float4 h2 = hs4[(c0 + 2) ^ (((c0 + 2) >> 3) & 7)];
      float4 h3 = hs4[(c0 + 3) ^ (((c0 + 3) >> 3) & 7)];
      for (int jb = wave * 4; jb < count; jb += NWAVE * 4) {
        int n_ = count - jb;
        const uint4* base = W8 + (((size_t)(start + jb)) << 6) + lane;
        uint4 u0 = base[0];
        uint4 u1 = base[n_ > 1 ? 64 : 0];
        uint4 u2 = base[n_ > 2 ? 128 : 0];
        uint4 u3 = base[n_ > 3 ? 192 : 0];
        float a0 = dot16_fp8(u0, h0, h1, h2, h3);
        float a1 = dot16_fp8(u1, h0, h1, h2, h3);
        float a2 = dot16_fp8(u2, h0, h1, h2, h3);
        float a3 = dot16_fp8(u3, h0, h1, h2, h3);
        a0 = wred64(a0); a1 = wred64(a1); a2 = wred64(a2); a3 = wred64(a3);
        if (lane == 0) {
          e_lds[jb] = a0 + b_out[start + jb];
          if (n_ > 1) e_lds[jb + 1] = a1 + b_out[start + jb + 1];
          if (n_ > 2) e_lds[jb + 2] = a2 + b_out[start + jb + 2];
          if (n_ > 3) e_lds[jb + 3] = a3 + b_out[start + jb + 3];
        }
      }
    } else {
      for (int jb = wave * 4; jb < count; jb += NWAVE * 4) {
        int n_ = count - jb;
        const float4* r0 = (const float4*)(W_out + (size_t)(start + jb) * HDIM);
        const float4* r1 = (const float4*)(W_out + (size_t)(start + jb + (n_ > 1 ? 1 : 0)) * HDIM);
        const float4* r2 = (const float4*)(W_out + (size_t)(start + jb + (n_ > 2 ? 2 : 0)) * HDIM);
        const float4* r3 = (const float4*)(W_out + (size_t)(start + jb + (n_ > 3 ? 3 : 0)) * HDIM);
        float a0 = 0.f, a1 = 0.f, a2 = 0.f, a3 = 0.f;
#pragma unroll
        for (int c = 0; c < 4; ++c) {
          float4 hh = h4[lane + 64 * c];
          a0 += dot4(r0[lane + 64 * c], hh);
          a1 += dot4(r1[lane + 64 * c], hh);
          a2 += dot4(r2[lane + 64 * c], hh);
          a3 += dot4(r3[lane + 64 * c], hh);
        }
        a0 = wred64(a0); a1 = wred64(a1); a2 = wred64(a2); a3 = wred64(a3);
        if (lane == 0) {
          e_lds[jb] = a0 + b_out[start + jb];
          if (n_ > 1) e_lds[jb + 1] = a1 + b_out[start + jb + 1];
          if (n_ > 2) e_lds[jb + 2] = a2 + b_out[start + jb + 2];
          if (n_ > 3) e_lds[jb + 3] = a3 + b_out[start + jb + 3];
        }
      }
    }
    __syncthreads();

    // ---- block-local max/argmax of scan logits (lowest-index ties) ----
    float m_soft; int i_soft;
    {
      float v = -INFINITY; int idx = 0x7fffffff;
      if (tid < count) { v = e_lds[tid]; idx = start + tid; }
      wmax64(v, idx);
      if (lane == 0) { red_v[wave] = v; red_i[wave] = idx; }
    }
    __syncthreads();
    {
      float v = red_v[0]; int idx = red_i[0];
#pragma unroll
      for (int w = 1; w < NWAVE; ++w) {
        float v2 = red_v[w]; int i2 = red_i[w];
        if (v2 > v || (v2 == v && i2 < idx)) { v = v2; idx = i2; }
      }
      m_soft = v; i_soft = idx;
    }

    // ---- exp partial ----
    float pe = (tid < count) ? expf(e_lds[tid] - m_soft) : 0.f;
    {
      float ls = wred64(pe);
      if (lane == 0) red_s[wave] = ls;
    }

    // ---- fp32 rescore of near-max candidates (Q8; adaptive window) ----
    float m_arg = m_soft; int i_arg = i_soft;
    if (Q8) {
      float nrm2 = 0.f;
#pragma unroll
      for (int w = 0; w < NWAVE; ++w) nrm2 += red_n[w];
      float delta = 0.01f * sqrtf(nrm2) + 1e-7f;   // ~14 sigma of fp8 logit err
      float bv = -INFINITY; int bi = 0x7fffffff;
      for (int j = wave; j < count; j += NWAVE) {  // wave-uniform condition
        if (e_lds[j] >= m_soft - delta) {
          const float4* w = (const float4*)(W_out + (size_t)(start + j) * HDIM);
          float a = 0.f;
#pragma unroll
          for (int c = 0; c < 4; ++c) a += dot4(w[lane + 64 * c], h4[lane + 64 * c]);
          a = wred64(a) + b_out[start + j];
          if (a > bv) { bv = a; bi = start + j; } // ascending j => min idx on ties
        }
      }
      if (lane == 0) { red_v2[wave] = bv; red_i2[wave] = bi; }
    }
    __syncthreads();
    float lsum = 0.f;
#pragma unroll
    for (int w = 0; w < NWAVE; ++w) lsum += red_s[w];
    if (Q8) {
      float v = red_v2[0]; int idx = red_i2[0];
#pragma unroll
      for (int w = 1; w < NWAVE; ++w) {
        float v2 = red_v2[w]; int i2 = red_i2[w];
        if (v2 > v || (v2 == v && i2 < idx)) { v = v2; idx = i2; }
      }
      m_arg = v; i_arg = idx;
    }

    if (tid == 0) {
      astf(&psoft[blk], m_soft); astf(&pargv[blk], m_arg);
      asti(&pargi[blk], i_arg);  astf(&psum[blk], lsum);
    }

    // ---- barrier B with payload: block0 reduces once, publishes result ----
    ++rnd;
    __syncthreads();
    int tokn; float lmax, Ssum;
    if (blk == 0) {
      if (tid >= 1 && tid < NBLK) {
        const uint* slot = arrive + tid * 32;
        while (ald(slot) < rnd) __builtin_amdgcn_s_sleep(1);
      }
      __syncthreads();
      float v = -INFINITY, m = -INFINITY, mysum = 0.f, myms = 0.f;
      int idx = 0x7fffffff;
      if (tid < NBLK) {
        v     = aldf(&pargv[tid]);
        idx   = aldi(&pargi[tid]);
        m     = aldf(&psoft[tid]);
        mysum = aldf(&psum[tid]);
        myms  = m;
      }
      wmax64(v, idx);
      float mm = wvmax64(m);
      if (lane == 0 && wave < 4) { red_v[wave] = v; red_i[wave] = idx; red_m[wave] = mm; }
      __syncthreads();
      {
        float vv = red_v[0]; int ii2 = red_i[0]; float mmax = red_m[0];
#pragma unroll
        for (int w = 1; w < 4; ++w) {
          float v2 = red_v[w]; int i2 = red_i[w];
          if (v2 > vv || (v2 == vv && i2 < ii2)) { vv = v2; ii2 = i2; }
          mmax = fmaxf(mmax, red_m[w]);
        }
        tokn = ii2; lmax = mmax;
      }
      {
        float s = (tid < NBLK) ? mysum * expf(myms - lmax) : 0.f;
        s = wred64(s);
        if (lane == 0 && wave < 4) red_s[wave] = s;
      }
      __syncthreads();
      Ssum = red_s[0] + red_s[1] + red_s[2] + red_s[3];
      if (tid < 32) {
        uint* dl = done + tid * 32;
        ast(dl + 1, (uint)tokn);
        ast(dl + 2, __float_as_uint(lmax));
        ast(dl + 3, __float_as_uint(Ssum));
        fence_vm();                 // payload at IC before flag
        ast(dl, rnd);
      }
    } else {
      if (tid == 0) {
        fence_vm();
        ast(arrive + blk * 32, rnd);
        const uint* dl = done + (blk >> 3) * 32;
        while (ald(dl) < rnd) __builtin_amdgcn_s_sleep(1);
        sh_tok  = (int)ald(dl + 1);
        sh_lmax = __uint_as_float(ald(dl + 2));
        sh_S    = __uint_as_float(ald(dl + 3));
      }
      __syncthreads();
      tokn = sh_tok; lmax = sh_lmax; Ssum = sh_S;
    }

    // prefetch next token's embedding row (hides under the prob stores)
    if (tid < 256)
      pfx = ((const float4*)(Wemb_dec + (size_t)tokn * HDIM))[tid];

    float scale = expf(m_soft - lmax) / Ssum;
    if (tid < count)
      out[(size_t)nsteps + (size_t)t * VDIM + start + tid] = pe * scale;
    if (blk == 0 && tid == 0) out[t] = (float)tokn;
  }
}

extern "C" void kernel_launch(void* const* d_in, const int* in_sizes, int n_in,
                              void* d_out, int out_size, void* d_ws, size_t ws_size,
                              hipStream_t stream) {
  const int*   source      = (const int*)d_in[0];
  const int*   n_steps_p   = (const int*)d_in[1];
  const int*   start_tok_p = (const int*)d_in[2];
  const float* Wemb_enc    = (const float*)d_in[3];
  const float* W_ih_e      = (const float*)d_in[4];
  const float* W_hh_e      = (const float*)d_in[5];
  const float* b_ih_e      = (const float*)d_in[6];
  const float* b_hh_e      = (const float*)d_in[7];
  const float* Wemb_dec    = (const float*)d_in[8];
  const float* W_ih_d      = (const float*)d_in[9];
  const float* W_hh_d      = (const float*)d_in[10];
  const float* b_ih_d      = (const float*)d_in[11];
  const float* b_hh_d      = (const float*)d_in[12];
  const float* W_out       = (const float*)d_in[13];
  const float* b_out       = (const float*)d_in[14];
  float*       out         = (float*)d_out;
  int          S           = in_sizes[0];

  char* ws = (char*)d_ws;
  float* gates  = (float*)(ws + WS_GATES);
  float* psoft  = (float*)(ws + WS_PSOFT);
  float* pargv  = (float*)(ws + WS_PARGV);
  int*   pargi  = (int*)  (ws + WS_PARGI);
  float* psum   = (float*)(ws + WS_PSUM);
  uint*  arrive = (uint*) (ws + WS_ARRIVE);
  uint*  done   = (uint*) (ws + WS_DONE);
  uint4* W8     = (uint4*)(ws + WS_W8);

  bool use_q8 = ws_size >= (size_t)WS_W8 + W8_BYTES;

  // zero barrier slots/done (+partials) every launch -> replay-deterministic
  hipMemsetAsync(ws + WS_ZOFF, 0, WS_ZLEN, stream);

  if (use_q8)
    conv8_kernel<<<2048, 256, 0, stream>>>(W_out, W8, VDIM * HDIM / 16);

  void* args[] = { &source, &S, &n_steps_p, &start_tok_p, &Wemb_enc,
                   &W_ih_e, &W_hh_e, &b_ih_e, &b_hh_e, &Wemb_dec,
                   &W_ih_d, &W_hh_d, &b_ih_d, &b_hh_d, &W_out, &b_out,
                   &W8, &out, &gates, &psoft, &pargv, &pargi, &psum,
                   &arrive, &done };

  void* kfn = use_q8 ? (void*)seq2seq_kernel<1> : (void*)seq2seq_kernel<0>;
  hipLaunchCooperativeKernel(kfn, dim3(NBLK), dim3(NTHR), args, 0, stream);
}